// Round 9
// baseline (40.036 us; speedup 1.0000x reference)
//
#include <hip/hip_runtime.h>
#include <math.h>

#define BATCH 64
#define LSEQ 4096
#define CH 128
#define NCHUNK 8
#define CHROWS (LSEQ / NCHUNK)   // 512
#define TROWS (CHROWS / 8)       // 64 rows per thread
#define NRECENT 1024             // rows 3072.. = chunks 6,7

// ---------------- Kernel 1: per-chunk partial sums ----------------
// grid (NCHUNK, BATCH) = 512 blocks, block 256 = (c4: 32) x (ty: 8)
// ws layout per (b,chunk): 5 slots x 128 ch: 0:sx 1:sx2 2:sx3 3:sd 4:sd2
__global__ __launch_bounds__(256) void k_stats_partial(
    const float* __restrict__ x, float* __restrict__ ws) {
  const int tid = threadIdx.x;
  const int c4 = tid & 31;
  const int ty = tid >> 5;
  const int chk = blockIdx.x;
  const int b = blockIdx.y;
  const int ts = chk * CHROWS + ty * TROWS;

  const float4* px =
      reinterpret_cast<const float4*>(x + ((size_t)b * LSEQ + ts) * CH) + c4;
  const int rowstep = CH / 4;

  float sx[4] = {0, 0, 0, 0}, sx2[4] = {0, 0, 0, 0}, sx3[4] = {0, 0, 0, 0};
  float sd2[4] = {0, 0, 0, 0};
  float pv[4], first[4], sd[4];

  float4 v0 = px[0];
  pv[0] = first[0] = v0.x;
  pv[1] = first[1] = v0.y;
  pv[2] = first[2] = v0.z;
  pv[3] = first[3] = v0.w;
#pragma unroll
  for (int k = 0; k < 4; k++) {
    float f = pv[k], ff = f * f;
    sx[k] += f; sx2[k] += ff; sx3[k] = fmaf(ff, f, sx3[k]);
  }
#pragma unroll 8
  for (int i = 1; i < TROWS; i++) {
    float4 u = px[i * rowstep];
    float cur[4] = {u.x, u.y, u.z, u.w};
#pragma unroll
    for (int k = 0; k < 4; k++) {
      float f = cur[k], ff = f * f;
      sx[k] += f; sx2[k] += ff; sx3[k] = fmaf(ff, f, sx3[k]);
      float d = f - pv[k];
      sd2[k] = fmaf(d, d, sd2[k]);
      pv[k] = f;
    }
  }
  if (ts + TROWS < LSEQ) {
    float4 u = px[TROWS * rowstep];
    float cur[4] = {u.x, u.y, u.z, u.w};
#pragma unroll
    for (int k = 0; k < 4; k++) {
      float d = cur[k] - pv[k];
      sd2[k] = fmaf(d, d, sd2[k]);
      sd[k] = cur[k] - first[k];   // telescoped sum of this thread's diffs
    }
  } else {
#pragma unroll
    for (int k = 0; k < 4; k++) sd[k] = pv[k] - first[k];
  }

  float vals[20];
#pragma unroll
  for (int k = 0; k < 4; k++) {
    vals[0 + k] = sx[k];
    vals[4 + k] = sx2[k];
    vals[8 + k] = sx3[k];
    vals[12 + k] = sd[k];
    vals[16 + k] = sd2[k];
  }
#pragma unroll
  for (int j = 0; j < 20; j++) vals[j] += __shfl_xor(vals[j], 32);

  __shared__ float4 red[5][4][32];
  const int w = tid >> 6;
  const int lane = tid & 63;
  if (lane < 32) {
#pragma unroll
    for (int s = 0; s < 5; s++)
      red[s][w][c4] = make_float4(vals[s * 4 + 0], vals[s * 4 + 1],
                                  vals[s * 4 + 2], vals[s * 4 + 3]);
  }
  __syncthreads();
  if (tid < 160) {
    const int s = tid >> 5, c = tid & 31;
    float4 r = red[s][0][c];
    float4 r1 = red[s][1][c], r2 = red[s][2][c], r3 = red[s][3][c];
    r.x += r1.x + r2.x + r3.x;
    r.y += r1.y + r2.y + r3.y;
    r.z += r1.z + r2.z + r3.z;
    r.w += r1.w + r2.w + r3.w;
    float* wsb = ws + ((size_t)(b * NCHUNK + chk) * 5 + s) * CH;
    reinterpret_cast<float4*>(wsb)[c] = r;
  }
}

// ---------------- Kernel 2: finalize stats + MLP (1024 thr, deep split-K) --
// grid (BATCH), block 1024: f = tid&127, g = tid>>7 (0..7)
__global__ __launch_bounds__(1024) void k_stats_mlp(
    const float* __restrict__ ws,
    const float* __restrict__ W1, const float* __restrict__ b1,
    const float* __restrict__ W2, const float* __restrict__ b2,
    const float* __restrict__ W3, const float* __restrict__ b3,
    float* __restrict__ out) {
  const int b = blockIdx.x;
  const int tid = threadIdx.x;
  const int f = tid & 127;
  const int g = tid >> 7;  // 0..7

  __shared__ float part[5][8][CH];
  __shared__ float stats[6 * CH];
  __shared__ float h1p[8][CH];
  __shared__ float h1[CH];
  __shared__ float h2p[32][32];
  __shared__ float h2[32];
  __shared__ float l3p[8][CH];

  // ---- chunk reduce: group g owns chunk g for channel f ----
  {
    const float* p = ws + ((size_t)(b * NCHUNK + g) * 5) * CH + f;
    part[0][g][f] = p[0 * CH];
    part[1][g][f] = p[1 * CH];
    part[2][g][f] = p[2 * CH];
    part[3][g][f] = p[3 * CH];
    part[4][g][f] = p[4 * CH];
  }
  __syncthreads();

  if (tid < CH) {
    float t0 = 0, t1 = 0, t2 = 0, t3 = 0, t4 = 0, t5 = 0, t6 = 0;
#pragma unroll
    for (int k = 0; k < 8; k++) {
      float a0 = part[0][k][tid], a1 = part[1][k][tid];
      t0 += a0; t1 += a1;
      t2 += part[2][k][tid];
      t3 += part[3][k][tid];
      t4 += part[4][k][tid];
      if (k >= 6) { t5 += a0; t6 += a1; }  // recent = chunks 6,7
    }

    const float Lf = (float)LSEQ;
    float mean = t0 / Lf;
    float var = fmaxf(t1 - Lf * mean * mean, 0.f) / (Lf - 1.f);
    float stdE = sqrtf(var) + 1e-8f;
    float m3 = t2 / Lf - 3.f * mean * (t1 / Lf) + 2.f * mean * mean * mean;
    float skew = m3 / (stdE * stdE * stdE);
    const float nd = (float)(LSEQ - 1);
    float dmean = t3 / nd;
    float dvar = fmaxf(t4 - nd * dmean * dmean, 0.f) / (nd - 1.f);
    float dstd = sqrtf(dvar);
    const float nr = (float)NRECENT;
    float rmean = t5 / nr;
    float rvar = fmaxf(t6 - nr * rmean * rmean, 0.f) / (nr - 1.f);
    float rstd = sqrtf(rvar) + 1e-8f;

    stats[0 * CH + tid] = mean;
    stats[1 * CH + tid] = stdE;
    stats[2 * CH + tid] = skew;
    stats[3 * CH + tid] = dstd;
    stats[4 * CH + tid] = rmean;
    stats[5 * CH + tid] = rstd;
  }
  __syncthreads();

  // ---- layer 1: (768)@(768,128); group g covers k in [96g, 96g+96) ----
  {
    const int k0 = 96 * g;
    float a0 = 0, a1 = 0, a2 = 0, a3 = 0;
#pragma unroll 6
    for (int k = 0; k < 96; k += 4) {
      a0 = fmaf(stats[k0 + k + 0], W1[(size_t)(k0 + k + 0) * 128 + f], a0);
      a1 = fmaf(stats[k0 + k + 1], W1[(size_t)(k0 + k + 1) * 128 + f], a1);
      a2 = fmaf(stats[k0 + k + 2], W1[(size_t)(k0 + k + 2) * 128 + f], a2);
      a3 = fmaf(stats[k0 + k + 3], W1[(size_t)(k0 + k + 3) * 128 + f], a3);
    }
    h1p[g][f] = (a0 + a1) + (a2 + a3);
  }
  __syncthreads();
  if (tid < CH) {
    float a = b1[tid];
#pragma unroll
    for (int k = 0; k < 8; k++) a += h1p[k][tid];
    h1[tid] = 0.5f * a * (1.f + erff(a * 0.70710678118654752f));
  }
  __syncthreads();

  // ---- layer 2: (128)@(128,32); 32-way split-K ----
  {
    const int f2 = tid & 31, p2 = tid >> 5;  // k in [4p2, 4p2+4)
    float a0 = 0, a1 = 0;
#pragma unroll
    for (int k = 4 * p2; k < 4 * p2 + 4; k += 2) {
      a0 = fmaf(h1[k], W2[k * 32 + f2], a0);
      a1 = fmaf(h1[k + 1], W2[(k + 1) * 32 + f2], a1);
    }
    h2p[p2][f2] = a0 + a1;
  }
  __syncthreads();
  if (tid < 32) {
    float a = b2[tid];
#pragma unroll
    for (int p2 = 0; p2 < 32; p2++) a += h2p[p2][tid];
    h2[tid] = 0.5f * a * (1.f + erff(a * 0.70710678118654752f));
  }
  __syncthreads();

  // ---- layer 3: (32)@(32,128) + sigmoid; 8-way split-K ----
  {
    float a0 = 0, a1 = 0;
#pragma unroll
    for (int j = 4 * g; j < 4 * g + 4; j += 2) {
      a0 = fmaf(h2[j], W3[j * 128 + f], a0);
      a1 = fmaf(h2[j + 1], W3[(j + 1) * 128 + f], a1);
    }
    l3p[g][f] = a0 + a1;
  }
  __syncthreads();
  if (tid < CH) {
    float a = b3[tid];
#pragma unroll
    for (int k = 0; k < 8; k++) a += l3p[k][tid];
    out[(size_t)b * CH + tid] = 1.f / (1.f + expf(-a));
  }
}

extern "C" void kernel_launch(void* const* d_in, const int* in_sizes, int n_in,
                              void* d_out, int out_size, void* d_ws,
                              size_t ws_size, hipStream_t stream) {
  const float* x = (const float*)d_in[0];
  const float* W1 = (const float*)d_in[1];
  const float* b1 = (const float*)d_in[2];
  const float* W2 = (const float*)d_in[3];
  const float* b2 = (const float*)d_in[4];
  const float* W3 = (const float*)d_in[5];
  const float* b3 = (const float*)d_in[6];
  float* out = (float*)d_out;
  float* ws = (float*)d_ws;

  dim3 g1(NCHUNK, BATCH);
  k_stats_partial<<<g1, 256, 0, stream>>>(x, ws);
  k_stats_mlp<<<BATCH, 1024, 0, stream>>>(ws, W1, b1, W2, b2, W3, b3, out);
}

// Round 10
// 34.815 us; speedup vs baseline: 1.1500x; 1.1500x over previous
//
#include <hip/hip_runtime.h>
#include <math.h>

#define BATCH 64
#define LSEQ 4096
#define CH 128
#define NCHUNK 16
#define CHROWS (LSEQ / NCHUNK)   // 256
#define TROWS (CHROWS / 8)       // 32 rows per thread
#define NRECENT 1024             // rows 3072.. = chunks 12..15 = groups 6,7

// ---------------- Kernel 1: per-chunk partial sums ----------------
// grid (NCHUNK, BATCH) = 1024 blocks, block 256 = (c4: 32) x (ty: 8)
// 4 blocks/CU = 16 waves/CU (proven optimum, r8 vs r6/r9).
// ws layout per (b,chunk): 5 slots x 128 ch: 0:sx 1:sx2 2:sx3 3:sd 4:sd2
__global__ __launch_bounds__(256) void k_stats_partial(
    const float* __restrict__ x, float* __restrict__ ws) {
  const int tid = threadIdx.x;
  const int c4 = tid & 31;
  const int ty = tid >> 5;
  const int chk = blockIdx.x;
  const int b = blockIdx.y;
  const int ts = chk * CHROWS + ty * TROWS;

  const float4* px =
      reinterpret_cast<const float4*>(x + ((size_t)b * LSEQ + ts) * CH) + c4;
  const int rowstep = CH / 4;

  float sx[4] = {0, 0, 0, 0}, sx2[4] = {0, 0, 0, 0}, sx3[4] = {0, 0, 0, 0};
  float sd2[4] = {0, 0, 0, 0};
  float pv[4], first[4], sd[4];

  float4 v0 = px[0];
  pv[0] = first[0] = v0.x;
  pv[1] = first[1] = v0.y;
  pv[2] = first[2] = v0.z;
  pv[3] = first[3] = v0.w;
#pragma unroll
  for (int k = 0; k < 4; k++) {
    float f = pv[k], ff = f * f;
    sx[k] += f; sx2[k] += ff; sx3[k] = fmaf(ff, f, sx3[k]);
  }
#pragma unroll 8
  for (int i = 1; i < TROWS; i++) {
    float4 u = px[i * rowstep];
    float cur[4] = {u.x, u.y, u.z, u.w};
#pragma unroll
    for (int k = 0; k < 4; k++) {
      float f = cur[k], ff = f * f;
      sx[k] += f; sx2[k] += ff; sx3[k] = fmaf(ff, f, sx3[k]);
      float d = f - pv[k];
      sd2[k] = fmaf(d, d, sd2[k]);
      pv[k] = f;
    }
  }
  if (ts + TROWS < LSEQ) {
    float4 u = px[TROWS * rowstep];
    float cur[4] = {u.x, u.y, u.z, u.w};
#pragma unroll
    for (int k = 0; k < 4; k++) {
      float d = cur[k] - pv[k];
      sd2[k] = fmaf(d, d, sd2[k]);
      sd[k] = cur[k] - first[k];   // telescoped sum of this thread's diffs
    }
  } else {
#pragma unroll
    for (int k = 0; k < 4; k++) sd[k] = pv[k] - first[k];
  }

  float vals[20];
#pragma unroll
  for (int k = 0; k < 4; k++) {
    vals[0 + k] = sx[k];
    vals[4 + k] = sx2[k];
    vals[8 + k] = sx3[k];
    vals[12 + k] = sd[k];
    vals[16 + k] = sd2[k];
  }
#pragma unroll
  for (int j = 0; j < 20; j++) vals[j] += __shfl_xor(vals[j], 32);

  __shared__ float4 red[5][4][32];
  const int w = tid >> 6;
  const int lane = tid & 63;
  if (lane < 32) {
#pragma unroll
    for (int s = 0; s < 5; s++)
      red[s][w][c4] = make_float4(vals[s * 4 + 0], vals[s * 4 + 1],
                                  vals[s * 4 + 2], vals[s * 4 + 3]);
  }
  __syncthreads();
  if (tid < 160) {
    const int s = tid >> 5, c = tid & 31;
    float4 r = red[s][0][c];
    float4 r1 = red[s][1][c], r2 = red[s][2][c], r3 = red[s][3][c];
    r.x += r1.x + r2.x + r3.x;
    r.y += r1.y + r2.y + r3.y;
    r.z += r1.z + r2.z + r3.z;
    r.w += r1.w + r2.w + r3.w;
    float* wsb = ws + ((size_t)(b * NCHUNK + chk) * 5 + s) * CH;
    reinterpret_cast<float4*>(wsb)[c] = r;
  }
}

// ---------------- Kernel 2: finalize stats + MLP (1024 thr, deep split-K) --
// grid (BATCH), block 1024: f = tid&127, g = tid>>7 (0..7)
__global__ __launch_bounds__(1024) void k_stats_mlp(
    const float* __restrict__ ws,
    const float* __restrict__ W1, const float* __restrict__ b1,
    const float* __restrict__ W2, const float* __restrict__ b2,
    const float* __restrict__ W3, const float* __restrict__ b3,
    float* __restrict__ out) {
  const int b = blockIdx.x;
  const int tid = threadIdx.x;
  const int f = tid & 127;
  const int g = tid >> 7;  // 0..7

  __shared__ float part[5][8][CH];
  __shared__ float stats[6 * CH];
  __shared__ float h1p[8][CH];
  __shared__ float h1[CH];
  __shared__ float h2p[32][32];
  __shared__ float h2[32];
  __shared__ float l3p[8][CH];

  // ---- chunk reduce: group g sums chunks [2g, 2g+2) for channel f ----
  {
    float t0 = 0, t1 = 0, t2 = 0, t3 = 0, t4 = 0;
#pragma unroll
    for (int chk = g * 2; chk < g * 2 + 2; chk++) {
      const float* p = ws + ((size_t)(b * NCHUNK + chk) * 5) * CH + f;
      t0 += p[0 * CH];
      t1 += p[1 * CH];
      t2 += p[2 * CH];
      t3 += p[3 * CH];
      t4 += p[4 * CH];
    }
    part[0][g][f] = t0;
    part[1][g][f] = t1;
    part[2][g][f] = t2;
    part[3][g][f] = t3;
    part[4][g][f] = t4;
  }
  __syncthreads();

  if (tid < CH) {
    float t0 = 0, t1 = 0, t2 = 0, t3 = 0, t4 = 0, t5 = 0, t6 = 0;
#pragma unroll
    for (int k = 0; k < 8; k++) {
      float a0 = part[0][k][tid], a1 = part[1][k][tid];
      t0 += a0; t1 += a1;
      t2 += part[2][k][tid];
      t3 += part[3][k][tid];
      t4 += part[4][k][tid];
      if (k >= 6) { t5 += a0; t6 += a1; }  // recent = chunks 12..15
    }

    const float Lf = (float)LSEQ;
    float mean = t0 / Lf;
    float var = fmaxf(t1 - Lf * mean * mean, 0.f) / (Lf - 1.f);
    float stdE = sqrtf(var) + 1e-8f;
    float m3 = t2 / Lf - 3.f * mean * (t1 / Lf) + 2.f * mean * mean * mean;
    float skew = m3 / (stdE * stdE * stdE);
    const float nd = (float)(LSEQ - 1);
    float dmean = t3 / nd;
    float dvar = fmaxf(t4 - nd * dmean * dmean, 0.f) / (nd - 1.f);
    float dstd = sqrtf(dvar);
    const float nr = (float)NRECENT;
    float rmean = t5 / nr;
    float rvar = fmaxf(t6 - nr * rmean * rmean, 0.f) / (nr - 1.f);
    float rstd = sqrtf(rvar) + 1e-8f;

    stats[0 * CH + tid] = mean;
    stats[1 * CH + tid] = stdE;
    stats[2 * CH + tid] = skew;
    stats[3 * CH + tid] = dstd;
    stats[4 * CH + tid] = rmean;
    stats[5 * CH + tid] = rstd;
  }
  __syncthreads();

  // ---- layer 1: (768)@(768,128); group g covers k in [96g, 96g+96) ----
  {
    const int k0 = 96 * g;
    float a0 = 0, a1 = 0, a2 = 0, a3 = 0;
#pragma unroll 6
    for (int k = 0; k < 96; k += 4) {
      a0 = fmaf(stats[k0 + k + 0], W1[(size_t)(k0 + k + 0) * 128 + f], a0);
      a1 = fmaf(stats[k0 + k + 1], W1[(size_t)(k0 + k + 1) * 128 + f], a1);
      a2 = fmaf(stats[k0 + k + 2], W1[(size_t)(k0 + k + 2) * 128 + f], a2);
      a3 = fmaf(stats[k0 + k + 3], W1[(size_t)(k0 + k + 3) * 128 + f], a3);
    }
    h1p[g][f] = (a0 + a1) + (a2 + a3);
  }
  __syncthreads();
  if (tid < CH) {
    float a = b1[tid];
#pragma unroll
    for (int k = 0; k < 8; k++) a += h1p[k][tid];
    h1[tid] = 0.5f * a * (1.f + erff(a * 0.70710678118654752f));
  }
  __syncthreads();

  // ---- layer 2: (128)@(128,32); 32-way split-K ----
  {
    const int f2 = tid & 31, p2 = tid >> 5;  // k in [4p2, 4p2+4)
    float a0 = 0, a1 = 0;
#pragma unroll
    for (int k = 4 * p2; k < 4 * p2 + 4; k += 2) {
      a0 = fmaf(h1[k], W2[k * 32 + f2], a0);
      a1 = fmaf(h1[k + 1], W2[(k + 1) * 32 + f2], a1);
    }
    h2p[p2][f2] = a0 + a1;
  }
  __syncthreads();
  if (tid < 32) {
    float a = b2[tid];
#pragma unroll
    for (int p2 = 0; p2 < 32; p2++) a += h2p[p2][tid];
    h2[tid] = 0.5f * a * (1.f + erff(a * 0.70710678118654752f));
  }
  __syncthreads();

  // ---- layer 3: (32)@(32,128) + sigmoid; 8-way split-K ----
  {
    float a0 = 0, a1 = 0;
#pragma unroll
    for (int j = 4 * g; j < 4 * g + 4; j += 2) {
      a0 = fmaf(h2[j], W3[j * 128 + f], a0);
      a1 = fmaf(h2[j + 1], W3[(j + 1) * 128 + f], a1);
    }
    l3p[g][f] = a0 + a1;
  }
  __syncthreads();
  if (tid < CH) {
    float a = b3[tid];
#pragma unroll
    for (int k = 0; k < 8; k++) a += l3p[k][tid];
    out[(size_t)b * CH + tid] = 1.f / (1.f + expf(-a));
  }
}

extern "C" void kernel_launch(void* const* d_in, const int* in_sizes, int n_in,
                              void* d_out, int out_size, void* d_ws,
                              size_t ws_size, hipStream_t stream) {
  const float* x = (const float*)d_in[0];
  const float* W1 = (const float*)d_in[1];
  const float* b1 = (const float*)d_in[2];
  const float* W2 = (const float*)d_in[3];
  const float* b2 = (const float*)d_in[4];
  const float* W3 = (const float*)d_in[5];
  const float* b3 = (const float*)d_in[6];
  float* out = (float*)d_out;
  float* ws = (float*)d_ws;

  dim3 g1(NCHUNK, BATCH);
  k_stats_partial<<<g1, 256, 0, stream>>>(x, ws);
  k_stats_mlp<<<BATCH, 1024, 0, stream>>>(ws, W1, b1, W2, b2, W3, b3, out);
}